// Round 5
// baseline (1390.406 us; speedup 1.0000x reference)
//
#include <hip/hip_runtime.h>
#include <hip/hip_bf16.h>
#include <stdint.h>

#define TOKENS 4096
#define DMODEL 1024
#define VOCAB  50257
#define KSEL   64
#define NSPLIT 16
#define BM 128
#define BN 128
#define BK 32
#define MTILES (TOKENS / BM)                       // 32
#define COLS_PER ((VOCAB + NSPLIT - 1) / NSPLIT)   // 3142
#define CAP 48
#define MERGE_THR 17
#define TSZ (BM * BK)                              // 4096 elems = 8KB per tile buf
#define INF __builtin_inff()

typedef unsigned short u16;
typedef __attribute__((ext_vector_type(8))) short bf16x8;
typedef __attribute__((ext_vector_type(4))) float f32x4;

#define GLOAD16(gp, lp) __builtin_amdgcn_global_load_lds( \
    (const __attribute__((address_space(1))) void*)(gp),  \
    (__attribute__((address_space(3))) void*)(lp), 16, 0, 0)
#define GLOAD4(gp, lp) __builtin_amdgcn_global_load_lds(  \
    (const __attribute__((address_space(1))) void*)(gp),  \
    (__attribute__((address_space(3))) void*)(lp), 4, 0, 0)

// counted-vmcnt barrier: keep younger staging loads in flight (T3/T4)
#define WAITB(N) do { asm volatile("s_waitcnt vmcnt(" #N ")" ::: "memory"); \
                      __builtin_amdgcn_s_barrier(); } while (0)
// LDS-visibility-only barrier: does NOT drain vmcnt (prologue loads survive)
#define LBAR() do { asm volatile("s_waitcnt lgkmcnt(0)" ::: "memory"); \
                    __builtin_amdgcn_s_barrier(); } while (0)

__device__ __forceinline__ u16 f2bf(float f) {
  uint32_t u = __float_as_uint(f);
  u = (u + 0x7fffu + ((u >> 16) & 1u)) >> 16;   // RNE
  return (u16)u;
}

// ---------------------------------------------------------------------------
// Kernel 1: x,b -> bf16 + fp32 squared norms. One block per row.
// ---------------------------------------------------------------------------
__global__ __launch_bounds__(256) void prep_kernel(
    const float* __restrict__ x, const float* __restrict__ b,
    u16* __restrict__ xh, u16* __restrict__ bh,
    float* __restrict__ xsq, float* __restrict__ bsq) {
  int row = blockIdx.x;
  int tid = threadIdx.x;
  const float* src;
  u16* dst;
  float* nrm;
  int r;
  if (row < TOKENS) {
    r = row; src = x + (size_t)r * DMODEL; dst = xh + (size_t)r * DMODEL; nrm = xsq;
  } else {
    r = row - TOKENS; src = b + (size_t)r * DMODEL; dst = bh + (size_t)r * DMODEL; nrm = bsq;
  }
  float4 v = reinterpret_cast<const float4*>(src)[tid];
  float s = v.x * v.x + v.y * v.y + v.z * v.z + v.w * v.w;
  ushort4 h;
  h.x = f2bf(v.x); h.y = f2bf(v.y); h.z = f2bf(v.z); h.w = f2bf(v.w);
  reinterpret_cast<ushort4*>(dst)[tid] = h;
#pragma unroll
  for (int j = 1; j < 64; j <<= 1) s += __shfl_xor(s, j);
  __shared__ float acc4[4];
  if ((tid & 63) == 0) acc4[tid >> 6] = s;
  __syncthreads();
  if (tid == 0) nrm[r] = acc4[0] + acc4[1] + acc4[2] + acc4[3];
}

// ---------------------------------------------------------------------------
// merge_row: sort candidate buffer (cnt <= CAP=48 < 64), merge 64 smallest
// into sorted asc list value lstv. noinline: one code copy.
// ---------------------------------------------------------------------------
__device__ __attribute__((noinline)) float merge_row(float lstv, const float* cb, int cnt) {
  const int lane = threadIdx.x & 63;
  float v0 = (lane < cnt) ? cb[lane] : INF;
  // bitonic sort-64 asc
#pragma unroll
  for (int k = 2; k <= 64; k <<= 1) {
#pragma unroll
    for (int j = k >> 1; j > 0; j >>= 1) {
      float p = __shfl_xor(v0, j);
      bool keepmin = (((lane & j) == 0) == ((lane & k) == 0));
      v0 = keepmin ? fminf(v0, p) : fmaxf(v0, p);
    }
  }
  // bitonic top-64 merge: lstv (asc) vs v0 reversed
  float rev = __shfl(v0, 63 - lane);
  float m = fminf(lstv, rev);
#pragma unroll
  for (int j = 32; j > 0; j >>= 1) {
    float p = __shfl_xor(m, j);
    m = ((lane & j) == 0) ? fminf(m, p) : fmaxf(m, p);
  }
  return m;
}

// ---------------------------------------------------------------------------
// Kernel 2: 128x128 bf16 MFMA GEMM, BK=32, triple-buffered LDS tiles with
// counted vmcnt (2 K-steps in flight), fused streaming top-64.
// WAR-safe schedule: stage of tile t+2 is issued immediately AFTER the
// barrier at which all waves finished computing tile t-1 (same buffer).
// ---------------------------------------------------------------------------
__global__ __launch_bounds__(512, 4) void gemm_topk_kernel(
    const u16* __restrict__ xh, const u16* __restrict__ bh,
    const float* __restrict__ xsq, const float* __restrict__ bsqg,
    float* __restrict__ parts) {
  __shared__ u16 As[3 * TSZ];        // 24KB: 3 bufs of [128 rows][32 elems], swizzled
  __shared__ u16 Bs[3 * TSZ];        // 24KB
  __shared__ float cbuf[BM][CAP];    // 24KB
  __shared__ float bsq_s[2][BN];     // 1KB (parity by chunk)
  __shared__ float tau[BM];
  __shared__ int   ccnt[BM];
  __shared__ float xsq_s[BM];
  // total 74.5KB -> 2 blocks/CU (16 waves/CU)

  const int tid  = threadIdx.x;
  const int lane = tid & 63;
  const int wave = tid >> 6;            // 0..7
  // bijective XCD swizzle: 512 blocks = 64/XCD; each XCD owns 2 vocab splits
  const int bid  = (blockIdx.x & 7) * 64 + (blockIdx.x >> 3);
  const int mt   = bid & (MTILES - 1);
  const int ns   = bid >> 5;

  const int mrow0 = mt * BM;
  const int col0  = ns * COLS_PER;
  const int col1  = (col0 + COLS_PER < VOCAB) ? (col0 + COLS_PER) : VOCAB;
  const int nchunk = (col1 - col0 + BN - 1) / BN;

  // staging geometry: 8 segs of 16 rows x 64B per tile; wave stages seg=wave.
  // LDS slot s of row r holds global col-slot s ^ ((r>>1)&3)  (involution).
  const int stg_row = wave * 16 + (lane >> 2);
  const int stg_col = ((lane & 3) ^ ((lane >> 3) & 3)) << 3;
  const u16* a_src = xh + (size_t)(mrow0 + stg_row) * DMODEL + stg_col;
  int gc0 = col0 + stg_row; if (gc0 > VOCAB - 1) gc0 = VOCAB - 1;
  const u16* b_src = bh + (size_t)gc0 * DMODEL + stg_col;

#define STAGE_STEP(BB, KS) do {                         \
    GLOAD16(a_src + (KS), &As[(BB) + wave * 512]);      \
    GLOAD16(b_src + (KS), &Bs[(BB) + wave * 512]);      \
  } while (0)

#define STAGE_BSQ(CC) do {                                              \
    int c_ = col0 + (CC) * BN + lane;                                   \
    int cA_ = (c_ < VOCAB) ? c_ : (VOCAB - 1);                          \
    int cB_ = (c_ + 64 < VOCAB) ? (c_ + 64) : (VOCAB - 1);              \
    GLOAD4(bsqg + cA_, &bsq_s[(CC) & 1][0]);                            \
    GLOAD4(bsqg + cB_, &bsq_s[(CC) & 1][64]);                           \
  } while (0)

  // xsq read + LDS init BEFORE any counted gload (keeps vmcnt math clean)
  if (tid < BM) {
    float xv = xsq[mrow0 + tid];
    xsq_s[tid] = xv;
    tau[tid] = INF;
    ccnt[tid] = 0;
  }

  // chunk-0 prologue: bsq + K-steps 0,1  (6 loads/wave in flight)
  STAGE_BSQ(0);
  STAGE_STEP(0, 0);
  STAGE_STEP(TSZ, BK);

  float lst[16];
#pragma unroll
  for (int i = 0; i < 16; ++i) lst[i] = INF;

  const int g4 = lane >> 4, fr = lane & 15;
  const int wm = wave >> 1, wn = wave & 1;
  const int rj = g4 * 4;
  const int r0 = wm * 32 + wn * 16;
  auto rowoff = [&](int r) { return r * BK + ((g4 ^ ((r >> 1) & 3)) << 3); };
  const int fA0 = rowoff(wm * 32 + fr),      fA1 = rowoff(wm * 32 + 16 + fr);
  const int fB0 = rowoff(wn * 64 + fr),      fB1 = rowoff(wn * 64 + 16 + fr);
  const int fB2 = rowoff(wn * 64 + 32 + fr), fB3 = rowoff(wn * 64 + 48 + fr);

#define COMPUTE_STEP(BB) do {                                                  \
    bf16x8 a0 = *reinterpret_cast<const bf16x8*>(&As[(BB) + fA0]);             \
    bf16x8 a1 = *reinterpret_cast<const bf16x8*>(&As[(BB) + fA1]);             \
    bf16x8 b0 = *reinterpret_cast<const bf16x8*>(&Bs[(BB) + fB0]);             \
    bf16x8 b1 = *reinterpret_cast<const bf16x8*>(&Bs[(BB) + fB1]);             \
    bf16x8 b2 = *reinterpret_cast<const bf16x8*>(&Bs[(BB) + fB2]);             \
    bf16x8 b3 = *reinterpret_cast<const bf16x8*>(&Bs[(BB) + fB3]);             \
    __builtin_amdgcn_s_setprio(1);                                             \
    acc[0][0] = __builtin_amdgcn_mfma_f32_16x16x32_bf16(a0, b0, acc[0][0], 0, 0, 0); \
    acc[0][1] = __builtin_amdgcn_mfma_f32_16x16x32_bf16(a0, b1, acc[0][1], 0, 0, 0); \
    acc[0][2] = __builtin_amdgcn_mfma_f32_16x16x32_bf16(a0, b2, acc[0][2], 0, 0, 0); \
    acc[0][3] = __builtin_amdgcn_mfma_f32_16x16x32_bf16(a0, b3, acc[0][3], 0, 0, 0); \
    acc[1][0] = __builtin_amdgcn_mfma_f32_16x16x32_bf16(a1, b0, acc[1][0], 0, 0, 0); \
    acc[1][1] = __builtin_amdgcn_mfma_f32_16x16x32_bf16(a1, b1, acc[1][1], 0, 0, 0); \
    acc[1][2] = __builtin_amdgcn_mfma_f32_16x16x32_bf16(a1, b2, acc[1][2], 0, 0, 0); \
    acc[1][3] = __builtin_amdgcn_mfma_f32_16x16x32_bf16(a1, b3, acc[1][3], 0, 0, 0); \
    __builtin_amdgcn_s_setprio(0);                                             \
  } while (0)

#pragma unroll 1
  for (int ch = 0; ch < nchunk; ++ch) {
    const int cbase = col0 + ch * BN;
    f32x4 acc[2][4];
#pragma unroll
    for (int i = 0; i < 2; ++i)
#pragma unroll
      for (int j = 0; j < 4; ++j) acc[i][j] = (f32x4){0.f, 0.f, 0.f, 0.f};

    // K pipeline: 32 steps, tiles t in buf[t%3], staged 2 ahead.
    // Each step: WAITB (retire S_t; all waves done with C_{t-1}) ->
    //            STAGE S_{t+2} into buf[(t+2)%3] (== C_{t-1}'s buffer: WAR-safe)
    //            -> COMPUTE t.
#pragma unroll 1
    for (int i = 0; i < 10; ++i) {
      const int ksb = i * 96;
      WAITB(2);                          // t=3i resident; S_{t+1} stays in flight
      STAGE_STEP(2 * TSZ, ksb + 64);     // stage t+2 -> buf2
      COMPUTE_STEP(0);                   // compute t   (buf0)
      WAITB(2);
      STAGE_STEP(0, ksb + 96);           // stage t+3 -> buf0
      COMPUTE_STEP(TSZ);                 // compute t+1 (buf1)
      WAITB(2);
      STAGE_STEP(TSZ, ksb + 128);        // stage t+4 -> buf1
      COMPUTE_STEP(2 * TSZ);             // compute t+2 (buf2)
    }
    WAITB(2);                            // t=30 resident (buf0); S31 in flight
    COMPUTE_STEP(0);
    WAITB(0);                            // t=31 (buf1), pipeline drained
    COMPUTE_STEP(TSZ);

    // ---- filter + merge: 4 phases of 32 cols (growth <= 16+32 <= CAP) ----
    const bool lastch = (ch == nchunk - 1);
#pragma unroll
    for (int p = 0; p < 4; ++p) {
      if (wn == (p >> 1)) {
#pragma unroll
        for (int f2 = 0; f2 < 2; ++f2) {
          const int fn = (p & 1) * 2 + f2;
          const int c = cbase + wn * 64 + fn * 16 + fr;
          const bool cv = (c < col1);
          const float bq = bsq_s[ch & 1][wn * 64 + fn * 16 + fr];
#pragma unroll
          for (int fm = 0; fm < 2; ++fm) {
#pragma unroll
            for (int j = 0; j < 4; ++j) {
              const int rl = wm * 32 + fm * 16 + rj + j;
              const float dist = xsq_s[rl] + bq - 2.0f * acc[fm][fn][j];
              if (cv && dist < tau[rl]) {
                int ix = atomicAdd(&ccnt[rl], 1);
                if (ix < CAP) cbuf[rl][ix] = dist;
              }
            }
          }
        }
      }
      LBAR();                             // pushes visible; vmcnt stays in flight
      if (p == 0 && !lastch) {            // T14 issue-early: next chunk prologue.
        STAGE_BSQ(ch + 1);                // buf0/buf1 readers (C30/C31) all passed
        int gcn = cbase + BN + stg_row;   // the LBAR above -> WAR-safe.
        if (gcn > VOCAB - 1) gcn = VOCAB - 1;
        b_src = bh + (size_t)gcn * DMODEL + stg_col;
        STAGE_STEP(0, 0);
        STAGE_STEP(TSZ, BK);
      }
      const bool force = lastch && (p == 3);
#pragma unroll
      for (int rl16 = 0; rl16 < 16; ++rl16) {   // static idx into lst (rule #20)
        const int r = r0 + rl16;
        const int cnt = ccnt[r];
        if (cnt >= MERGE_THR || (force && cnt > 0)) {
          float m = merge_row(lst[rl16], &cbuf[r][0], cnt);
          lst[rl16] = m;
          if (lane == 63) { tau[r] = m; ccnt[r] = 0; }
        }
      }
      LBAR();
    }
  }

  // write split-partial top-64 (sorted asc) from registers
#pragma unroll
  for (int rl16 = 0; rl16 < 16; ++rl16) {
    parts[(size_t)(mrow0 + r0 + rl16) * (NSPLIT * KSEL) + ns * KSEL + lane] = lst[rl16];
  }
#undef STAGE_STEP
#undef STAGE_BSQ
#undef COMPUTE_STEP
}

// ---------------------------------------------------------------------------
// Kernel 3: per row, tree-merge 16 sorted 64-lists down to the 64 smallest.
// ---------------------------------------------------------------------------
__device__ __forceinline__ float merge64(float a, float b, int lane) {
  float rev = __shfl(b, 63 - lane);
  float m = fminf(a, rev);
#pragma unroll
  for (int j = 32; j > 0; j >>= 1) {
    float p = __shfl_xor(m, j);
    m = ((lane & j) == 0) ? fminf(m, p) : fmaxf(m, p);
  }
  return m;
}

__global__ __launch_bounds__(256) void final_merge_kernel(
    const float* __restrict__ parts, float* __restrict__ out) {
  const int lane = threadIdx.x & 63;
  const int row = blockIdx.x * 4 + (threadIdx.x >> 6);
  float v[16];
#pragma unroll
  for (int i = 0; i < 16; ++i)
    v[i] = parts[(size_t)row * (NSPLIT * KSEL) + i * KSEL + lane];
#pragma unroll
  for (int i = 0; i < 8; ++i) v[i] = merge64(v[i], v[i + 8], lane);
#pragma unroll
  for (int i = 0; i < 4; ++i) v[i] = merge64(v[i], v[i + 4], lane);
#pragma unroll
  for (int i = 0; i < 2; ++i) v[i] = merge64(v[i], v[i + 2], lane);
  v[0] = merge64(v[0], v[1], lane);
  out[(size_t)row * KSEL + lane] = v[0];
}

// ---------------------------------------------------------------------------
extern "C" void kernel_launch(void* const* d_in, const int* in_sizes, int n_in,
                              void* d_out, int out_size, void* d_ws, size_t ws_size,
                              hipStream_t stream) {
  const float* x = (const float*)d_in[0];
  const float* b = (const float*)d_in[1];
  // d_in[2] = target (unused), d_in[3] = k (hardcoded 64)
  float* out = (float*)d_out;
  char* ws = (char*)d_ws;

  size_t off = 0;
  u16* xh = (u16*)(ws + off); off += (size_t)TOKENS * DMODEL * sizeof(u16);   // 8.4 MB
  u16* bh = (u16*)(ws + off); off += (size_t)VOCAB * DMODEL * sizeof(u16);    // 103 MB
  float* xsq = (float*)(ws + off); off += (size_t)TOKENS * sizeof(float);
  float* bsq = (float*)(ws + off); off += (((size_t)VOCAB * sizeof(float)) + 255) & ~(size_t)255;
  float* parts = (float*)(ws + off); off += (size_t)TOKENS * NSPLIT * KSEL * sizeof(float); // 16.8 MB

  prep_kernel<<<TOKENS + VOCAB, 256, 0, stream>>>(x, b, xh, bh, xsq, bsq);
  gemm_topk_kernel<<<MTILES * NSPLIT, 512, 0, stream>>>(xh, bh, xsq, bsq, parts);
  final_merge_kernel<<<TOKENS / 4, 256, 0, stream>>>(parts, out);
}

// Round 6
// 1217.757 us; speedup vs baseline: 1.1418x; 1.1418x over previous
//
#include <hip/hip_runtime.h>
#include <hip/hip_bf16.h>
#include <stdint.h>

#define TOKENS 4096
#define DMODEL 1024
#define VOCAB  50257
#define KSEL   64
#define NSPLIT 16
#define BM 128
#define BN 128
#define BK 64
#define MTILES (TOKENS / BM)                       // 32
#define COLS_PER ((VOCAB + NSPLIT - 1) / NSPLIT)   // 3142
#define CAP 80
#define MERGE_THR 17
#define INF __builtin_inff()

typedef unsigned short u16;
typedef __attribute__((ext_vector_type(8))) short bf16x8;
typedef __attribute__((ext_vector_type(4))) float f32x4;

// global -> LDS direct copy, 16B/lane. LDS dest is wave-uniform base + lane*16.
#define GLOAD16(gp, lp) __builtin_amdgcn_global_load_lds( \
    (const __attribute__((address_space(1))) void*)(gp),  \
    (__attribute__((address_space(3))) void*)(lp), 16, 0, 0)

__device__ __forceinline__ u16 f2bf(float f) {
  uint32_t u = __float_as_uint(f);
  u = (u + 0x7fffu + ((u >> 16) & 1u)) >> 16;   // RNE
  return (u16)u;
}

// order-preserving float <-> uint32 map (works for negatives too)
__device__ __forceinline__ uint32_t fenc(float f) {
  uint32_t b = __float_as_uint(f);
  return b ^ (uint32_t)(((int32_t)b >> 31) | 0x80000000u);
}
__device__ __forceinline__ float fdec(uint32_t k) {
  uint32_t b = k ^ (uint32_t)(((int32_t)(~k) >> 31) | 0x80000000u);
  return __uint_as_float(b);
}

// swizzled LDS element offset for logical (row, kElem); kElem multiple of 8.
__device__ __forceinline__ int swz(int row, int ke) {
  return row * BK + ((((ke) >> 3) ^ (row & 7)) << 3);
}

// ---------------------------------------------------------------------------
// Kernel 1: x,b -> bf16 + fp32 squared norms; init gtau. One block per row.
// ---------------------------------------------------------------------------
__global__ __launch_bounds__(256) void prep_kernel(
    const float* __restrict__ x, const float* __restrict__ b,
    u16* __restrict__ xh, u16* __restrict__ bh,
    float* __restrict__ xsq, float* __restrict__ bsq,
    uint32_t* __restrict__ gtau) {
  int row = blockIdx.x;
  int tid = threadIdx.x;
  const float* src;
  u16* dst;
  float* nrm;
  int r;
  if (row < TOKENS) {
    r = row; src = x + (size_t)r * DMODEL; dst = xh + (size_t)r * DMODEL; nrm = xsq;
    if (tid == 0) gtau[r] = 0xFF800000u;           // fenc(+INF)
  } else {
    r = row - TOKENS; src = b + (size_t)r * DMODEL; dst = bh + (size_t)r * DMODEL; nrm = bsq;
  }
  float4 v = reinterpret_cast<const float4*>(src)[tid];
  float s = v.x * v.x + v.y * v.y + v.z * v.z + v.w * v.w;
  ushort4 h;
  h.x = f2bf(v.x); h.y = f2bf(v.y); h.z = f2bf(v.z); h.w = f2bf(v.w);
  reinterpret_cast<ushort4*>(dst)[tid] = h;
#pragma unroll
  for (int j = 1; j < 64; j <<= 1) s += __shfl_xor(s, j);
  __shared__ float acc4[4];
  if ((tid & 63) == 0) acc4[tid >> 6] = s;
  __syncthreads();
  if (tid == 0) nrm[r] = acc4[0] + acc4[1] + acc4[2] + acc4[3];
}

// ---------------------------------------------------------------------------
// merge_row: sort candidate buffer (<=CAP, lane-held), merge 64 smallest into
// sorted asc list value lstv. noinline: one code copy.
// ---------------------------------------------------------------------------
__device__ __attribute__((noinline)) float merge_row(float lstv, const float* cb, int cnt) {
  const int lane = threadIdx.x & 63;
  float v0 = (lane < cnt) ? cb[lane] : INF;
  if (cnt > 64) {
    float v1 = (lane + 64 < cnt) ? cb[lane + 64] : INF;
    // full bitonic sort of 128 (virtual idx: v0->lane, v1->64+lane), asc
#pragma unroll
    for (int k = 2; k <= 128; k <<= 1) {
#pragma unroll
      for (int j = k >> 1; j > 0; j >>= 1) {
        if (j == 64) {
          float lo = fminf(v0, v1), hi = fmaxf(v0, v1);
          v0 = lo; v1 = hi;
        } else {
          {
            float p = __shfl_xor(v0, j);
            bool keepmin = (((lane & j) == 0) == ((lane & k) == 0));
            v0 = keepmin ? fminf(v0, p) : fmaxf(v0, p);
          }
          {
            float p = __shfl_xor(v1, j);
            bool keepmin = (((lane & j) == 0) == (((64 | lane) & k) == 0));
            v1 = keepmin ? fminf(v1, p) : fmaxf(v1, p);
          }
        }
      }
    }
  } else {
    // fast path: sort-64 asc (common case)
#pragma unroll
    for (int k = 2; k <= 64; k <<= 1) {
#pragma unroll
      for (int j = k >> 1; j > 0; j >>= 1) {
        float p = __shfl_xor(v0, j);
        bool keepmin = (((lane & j) == 0) == ((lane & k) == 0));
        v0 = keepmin ? fminf(v0, p) : fmaxf(v0, p);
      }
    }
  }
  // bitonic top-64 merge: lstv (asc across lanes) vs v0 reversed
  float rev = __shfl(v0, 63 - lane);
  float m = fminf(lstv, rev);
#pragma unroll
  for (int j = 32; j > 0; j >>= 1) {
    float p = __shfl_xor(m, j);
    m = ((lane & j) == 0) ? fminf(m, p) : fmaxf(m, p);
  }
  return m;
}

// ---------------------------------------------------------------------------
// Kernel 2: 128x128 bf16 MFMA GEMM (BK=64, 8 waves, global_load_lds w=16,
// both-sides LDS swizzle) fused with streaming top-64 and a CROSS-SPLIT
// shared per-row threshold gtau (atomicMin, order-preserving encoding).
// ---------------------------------------------------------------------------
__global__ __launch_bounds__(512, 4) void gemm_topk_kernel(
    const u16* __restrict__ xh, const u16* __restrict__ bh,
    const float* __restrict__ xsq, const float* __restrict__ bsq,
    uint32_t* __restrict__ gtau,
    float* __restrict__ parts) {
  __shared__ u16 As[BM * BK];        // linear [128][64] elems, swizzled slots, 16KB
  __shared__ u16 Bs[BN * BK];        // 16KB
  __shared__ float cbuf[BM][CAP];    // 40KB candidate buffers
  __shared__ float tau[BM];
  __shared__ int   ccnt[BM];
  __shared__ float xsq_s[BM];
  // total ~73.5KB -> 2 blocks/CU (16 waves/CU)

  const int tid  = threadIdx.x;
  const int lane = tid & 63;
  const int wave = tid >> 6;            // 0..7
  // bijective XCD swizzle (512 blocks = 64/XCD): each XCD owns 2 vocab splits
  const int bid  = (blockIdx.x & 7) * 64 + (blockIdx.x >> 3);
  const int mt   = bid & (MTILES - 1);
  const int ns   = bid >> 5;

  const int mrow0 = mt * BM;
  const int col0  = ns * COLS_PER;
  const int col1  = (col0 + COLS_PER < VOCAB) ? (col0 + COLS_PER) : VOCAB;
  const int nchunk = (col1 - col0 + BN - 1) / BN;

  // staging geometry: 16 segs of 1KB per tile; wave stages segs {wave, wave+8}.
  // source slot pre-swizzled so linear LDS dest holds swizzled layout (rule #21)
  const int srow = lane >> 3;                 // row within seg 0..7 (== row&7)
  const int scol = ((lane & 7) ^ srow) * 8;   // pre-swizzled 16B slot -> elem col

#define STAGE(ks_, cbase_) do {                                              \
    _Pragma("unroll")                                                        \
    for (int sg = 0; sg < 2; ++sg) {                                         \
      const int seg = wave + sg * 8;                                         \
      const int row = seg * 8 + srow;                                        \
      const u16* ga = xh + (size_t)(mrow0 + row) * DMODEL + (ks_) + scol;    \
      GLOAD16(ga, &As[seg * 512]);                                           \
      int gc = (cbase_) + row; if (gc > VOCAB - 1) gc = VOCAB - 1;           \
      const u16* gb = bh + (size_t)gc * DMODEL + (ks_) + scol;               \
      GLOAD16(gb, &Bs[seg * 512]);                                           \
    }                                                                        \
  } while (0)

  STAGE(0, col0);                       // prologue: first chunk's first K-step

  if (tid < BM) {
    tau[tid] = INF;
    ccnt[tid] = 0;
    xsq_s[tid] = xsq[mrow0 + tid];
  }

  float lst[16];                        // this wave's 16 rows' sorted top-64
#pragma unroll
  for (int i = 0; i < 16; ++i) lst[i] = INF;

  const int wm = wave >> 1, wn = wave & 1;
  const int fr = lane & 15;             // frag row (A) / col (B)
  const int kf = (lane >> 4) * 8;       // frag k element offset
  const int rj = (lane >> 4) * 4;       // C/D row base within frag
  const int r0 = wm * 32 + wn * 16;     // merge-owned rows base

#pragma unroll 1
  for (int ch = 0; ch < nchunk; ++ch) {
    const int cbase = col0 + ch * BN;
    f32x4 acc[2][4];
#pragma unroll
    for (int i = 0; i < 2; ++i)
#pragma unroll
      for (int j = 0; j < 4; ++j) acc[i][j] = (f32x4){0.f, 0.f, 0.f, 0.f};

#pragma unroll 1
    for (int ks = 0; ks < DMODEL; ks += BK) {
      if (ks) {
        __syncthreads();                // prev K-step reads done before overwrite
        STAGE(ks, cbase);
      }
      __syncthreads();                  // drains vmcnt(0): tiles ready
#pragma unroll
      for (int kk = 0; kk < BK; kk += 32) {
        bf16x8 a0 = *reinterpret_cast<const bf16x8*>(&As[swz(wm * 32 + fr,      kk + kf)]);
        bf16x8 a1 = *reinterpret_cast<const bf16x8*>(&As[swz(wm * 32 + 16 + fr, kk + kf)]);
        bf16x8 b0 = *reinterpret_cast<const bf16x8*>(&Bs[swz(wn * 64 + fr,      kk + kf)]);
        bf16x8 b1 = *reinterpret_cast<const bf16x8*>(&Bs[swz(wn * 64 + 16 + fr, kk + kf)]);
        bf16x8 b2 = *reinterpret_cast<const bf16x8*>(&Bs[swz(wn * 64 + 32 + fr, kk + kf)]);
        bf16x8 b3 = *reinterpret_cast<const bf16x8*>(&Bs[swz(wn * 64 + 48 + fr, kk + kf)]);
        acc[0][0] = __builtin_amdgcn_mfma_f32_16x16x32_bf16(a0, b0, acc[0][0], 0, 0, 0);
        acc[0][1] = __builtin_amdgcn_mfma_f32_16x16x32_bf16(a0, b1, acc[0][1], 0, 0, 0);
        acc[0][2] = __builtin_amdgcn_mfma_f32_16x16x32_bf16(a0, b2, acc[0][2], 0, 0, 0);
        acc[0][3] = __builtin_amdgcn_mfma_f32_16x16x32_bf16(a0, b3, acc[0][3], 0, 0, 0);
        acc[1][0] = __builtin_amdgcn_mfma_f32_16x16x32_bf16(a1, b0, acc[1][0], 0, 0, 0);
        acc[1][1] = __builtin_amdgcn_mfma_f32_16x16x32_bf16(a1, b1, acc[1][1], 0, 0, 0);
        acc[1][2] = __builtin_amdgcn_mfma_f32_16x16x32_bf16(a1, b2, acc[1][2], 0, 0, 0);
        acc[1][3] = __builtin_amdgcn_mfma_f32_16x16x32_bf16(a1, b3, acc[1][3], 0, 0, 0);
      }
    }

    __syncthreads();                    // ALL waves done reading tiles
    if (ch + 1 < nchunk) STAGE(0, cbase + BN);   // issue-early next chunk

    // refresh local tau from the cross-split shared threshold (stale-safe:
    // tau decreases monotonically; any upper bound is conservative-correct)
    if (tid < BM) {
      float gf = fdec(gtau[mrow0 + tid]);
      if (gf < tau[tid]) tau[tid] = gf;
    }

    // ---- filter + merge, two 64-col halves (caps cbuf growth at 64/half) ----
#pragma unroll
    for (int h = 0; h < 2; ++h) {
#pragma unroll
      for (int fm = 0; fm < 2; ++fm) {
#pragma unroll
        for (int fn2 = 0; fn2 < 2; ++fn2) {
          const int fn = h * 2 + fn2;
          const int c = cbase + wn * 64 + fn * 16 + fr;
          const bool cv = (c < col1);
          const float bq = cv ? bsq[c] : 0.f;
#pragma unroll
          for (int j = 0; j < 4; ++j) {
            const int rl = wm * 32 + fm * 16 + rj + j;
            const float dist = xsq_s[rl] + bq - 2.0f * acc[fm][fn][j];
            if (cv && dist < tau[rl]) {
              int ix = atomicAdd(&ccnt[rl], 1);
              if (ix < CAP) cbuf[rl][ix] = dist;   // policy guarantees ix < CAP
            }
          }
        }
      }
      __syncthreads();
      const bool last = (ch == nchunk - 1) && (h == 1);
#pragma unroll
      for (int rl16 = 0; rl16 < 16; ++rl16) {      // static idx into lst (rule #20)
        const int r = r0 + rl16;
        const int cnt = ccnt[r];
        if (cnt >= MERGE_THR || (last && cnt > 0)) {
          float m = merge_row(lst[rl16], &cbuf[r][0], cnt);
          lst[rl16] = m;
          if (lane == 63) {
            // publish local 64th-smallest; adopt the tighter of {ours, global}
            uint32_t old = atomicMin(&gtau[mrow0 + r], fenc(m));
            float og = fdec(old);
            tau[r] = fminf(m, og);
            ccnt[r] = 0;
          }
        }
      }
      if (h == 0) __syncthreads();      // h=1's visibility covered by next drain-sync
    }
  }

  // write split-partial top-64 (sorted asc) from registers
#pragma unroll
  for (int rl16 = 0; rl16 < 16; ++rl16) {
    parts[(size_t)(mrow0 + r0 + rl16) * (NSPLIT * KSEL) + ns * KSEL + lane] = lst[rl16];
  }
#undef STAGE
}

// ---------------------------------------------------------------------------
// Kernel 3: per row, tree-merge 16 sorted 64-lists down to the 64 smallest.
// ---------------------------------------------------------------------------
__device__ __forceinline__ float merge64(float a, float b, int lane) {
  float rev = __shfl(b, 63 - lane);
  float m = fminf(a, rev);
#pragma unroll
  for (int j = 32; j > 0; j >>= 1) {
    float p = __shfl_xor(m, j);
    m = ((lane & j) == 0) ? fminf(m, p) : fmaxf(m, p);
  }
  return m;
}

__global__ __launch_bounds__(256) void final_merge_kernel(
    const float* __restrict__ parts, float* __restrict__ out) {
  const int lane = threadIdx.x & 63;
  const int row = blockIdx.x * 4 + (threadIdx.x >> 6);
  float v[16];
#pragma unroll
  for (int i = 0; i < 16; ++i)
    v[i] = parts[(size_t)row * (NSPLIT * KSEL) + i * KSEL + lane];
#pragma unroll
  for (int i = 0; i < 8; ++i) v[i] = merge64(v[i], v[i + 8], lane);
#pragma unroll
  for (int i = 0; i < 4; ++i) v[i] = merge64(v[i], v[i + 4], lane);
#pragma unroll
  for (int i = 0; i < 2; ++i) v[i] = merge64(v[i], v[i + 2], lane);
  v[0] = merge64(v[0], v[1], lane);
  out[(size_t)row * KSEL + lane] = v[0];
}

// ---------------------------------------------------------------------------
extern "C" void kernel_launch(void* const* d_in, const int* in_sizes, int n_in,
                              void* d_out, int out_size, void* d_ws, size_t ws_size,
                              hipStream_t stream) {
  const float* x = (const float*)d_in[0];
  const float* b = (const float*)d_in[1];
  // d_in[2] = target (unused), d_in[3] = k (hardcoded 64)
  float* out = (float*)d_out;
  char* ws = (char*)d_ws;

  size_t off = 0;
  u16* xh = (u16*)(ws + off); off += (size_t)TOKENS * DMODEL * sizeof(u16);   // 8.4 MB
  u16* bh = (u16*)(ws + off); off += (size_t)VOCAB * DMODEL * sizeof(u16);    // 103 MB
  float* xsq = (float*)(ws + off); off += (size_t)TOKENS * sizeof(float);
  float* bsq = (float*)(ws + off); off += (((size_t)VOCAB * sizeof(float)) + 255) & ~(size_t)255;
  uint32_t* gtau = (uint32_t*)(ws + off); off += (size_t)TOKENS * sizeof(uint32_t);
  float* parts = (float*)(ws + off); off += (size_t)TOKENS * NSPLIT * KSEL * sizeof(float); // 16.8 MB

  prep_kernel<<<TOKENS + VOCAB, 256, 0, stream>>>(x, b, xh, bh, xsq, bsq, gtau);
  gemm_topk_kernel<<<MTILES * NSPLIT, 512, 0, stream>>>(xh, bh, xsq, bsq, gtau, parts);
  final_merge_kernel<<<TOKENS / 4, 256, 0, stream>>>(parts, out);
}